// Round 1
// baseline (699.918 us; speedup 1.0000x reference)
//
#include <hip/hip_runtime.h>
#include <hip/hip_bf16.h>
#include <stdint.h>

#define NN 4096
#define KK 4096
#define EPSV 1e-7f
#define NEGV -1e9f

typedef short short8 __attribute__((ext_vector_type(8)));
typedef __bf16 bf16x8 __attribute__((ext_vector_type(8)));
typedef float floatx4 __attribute__((ext_vector_type(4)));

__device__ __forceinline__ float bf2f(short s) {
    union { unsigned u; float f; } c;
    c.u = ((unsigned)(unsigned short)s) << 16;
    return c.f;
}
__device__ __forceinline__ short f2bf(float f) {
    union { float f; unsigned u; } c;
    c.f = f;
    unsigned r = (c.u + 0x7fffu + ((c.u >> 16) & 1u)) >> 16;
    return (short)r;
}

// nsq[j] = sum_i x[i][j]^2   (column sums of squares; nsq pre-zeroed)
__global__ __launch_bounds__(256) void col_norm_sq(const float* __restrict__ x,
                                                   float* __restrict__ nsq) {
    const int col = blockIdx.x * 256 + threadIdx.x;
    const int row0 = blockIdx.y * 128;
    float s = 0.f;
    for (int r = 0; r < 128; ++r) {
        float v = x[(size_t)(row0 + r) * NN + col];
        s = fmaf(v, v, s);
    }
    atomicAdd(&nsq[col], s);
}

// xb = bf16(x) row-major; xbT = bf16(x^T)
__global__ __launch_bounds__(256) void cast_transpose(const float* __restrict__ x,
                                                      short* __restrict__ xb,
                                                      short* __restrict__ xbT) {
    __shared__ short tile[64][66];  // +2 shorts pad -> bank = tx, conflict-free
    const int tx = threadIdx.x;     // 0..63
    const int ty = threadIdx.y;     // 0..3
    const int cb = blockIdx.x * 64;
    const int rb = blockIdx.y * 64;
#pragma unroll
    for (int i = 0; i < 16; ++i) {
        int r = ty + i * 4;
        short b = f2bf(x[(size_t)(rb + r) * NN + cb + tx]);
        xb[(size_t)(rb + r) * NN + cb + tx] = b;
        tile[r][tx] = b;
    }
    __syncthreads();
#pragma unroll
    for (int i = 0; i < 16; ++i) {
        int r = ty + i * 4;
        xbT[(size_t)(cb + r) * NN + rb + tx] = tile[tx][r];
    }
}

// NT GEMM: C[i][j] = sum_k A[i][k] * Bt[j][k], A/Bt bf16 [4096][4096].
// 128x128 block tile, BK=32, 4 waves in 2x2, each wave 64x64 via 4x4
// mfma_f32_16x16x32_bf16. LDS tile layout: [quad(k/8)][row][8 bf16] granules,
// contiguous in thread order for global_load_lds, conflict-free ds_read_b128.
// MODE 1: scores epilogue (beta/denorm + adj mask) -> bf16.  MODE 2: f32 out.
template <int MODE>
__global__ __launch_bounds__(256) void gemm_nt(const short* __restrict__ A,
                                               const short* __restrict__ Bt,
                                               void* __restrict__ Cout,
                                               const float* __restrict__ nsq,
                                               const float* __restrict__ adj,
                                               const float* __restrict__ betaPtr) {
    __shared__ __align__(16) short ldsA[4096];  // 4 quads * 128 rows * 8
    __shared__ __align__(16) short ldsB[4096];

    const int t = threadIdx.x;
    const int rowTile = blockIdx.y * 128;
    const int colTile = blockIdx.x * 128;

    floatx4 acc[4][4];
#pragma unroll
    for (int s = 0; s < 4; ++s)
#pragma unroll
        for (int n = 0; n < 4; ++n) acc[s][n] = (floatx4){0.f, 0.f, 0.f, 0.f};

    const int lane = t & 63;
    const int w = t >> 6;
    const int wm = (w >> 1) * 64;
    const int wn = (w & 1) * 64;
    const int q = lane >> 4;     // k-quad 0..3
    const int rsub = lane & 15;  // row/col within 16

    // staging: granule g (0..511) = [q=g>>7][row=g&127]; thread t does g=t and g=256+t
    const int q0 = t >> 7, r0 = t & 127;
    const int q1 = (256 + t) >> 7, r1 = (256 + t) & 127;
    const short* a0 = A + (size_t)(rowTile + r0) * KK + q0 * 8;
    const short* a1 = A + (size_t)(rowTile + r1) * KK + q1 * 8;
    const short* b0 = Bt + (size_t)(colTile + r0) * KK + q0 * 8;
    const short* b1 = Bt + (size_t)(colTile + r1) * KK + q1 * 8;
    short* la0 = ldsA + (size_t)t * 8;
    short* la1 = ldsA + (size_t)(256 + t) * 8;
    short* lb0 = ldsB + (size_t)t * 8;
    short* lb1 = ldsB + (size_t)(256 + t) * 8;

    for (int kb = 0; kb < KK; kb += 32) {
        __builtin_amdgcn_global_load_lds(
            (const __attribute__((address_space(1))) void*)(a0 + kb),
            (__attribute__((address_space(3))) void*)la0, 16, 0, 0);
        __builtin_amdgcn_global_load_lds(
            (const __attribute__((address_space(1))) void*)(a1 + kb),
            (__attribute__((address_space(3))) void*)la1, 16, 0, 0);
        __builtin_amdgcn_global_load_lds(
            (const __attribute__((address_space(1))) void*)(b0 + kb),
            (__attribute__((address_space(3))) void*)lb0, 16, 0, 0);
        __builtin_amdgcn_global_load_lds(
            (const __attribute__((address_space(1))) void*)(b1 + kb),
            (__attribute__((address_space(3))) void*)lb1, 16, 0, 0);
        __syncthreads();

        short8 af[4], bq[4];
#pragma unroll
        for (int s = 0; s < 4; ++s) {
            af[s] = *(const short8*)(ldsA + ((size_t)q * 128 + wm + s * 16 + rsub) * 8);
            bq[s] = *(const short8*)(ldsB + ((size_t)q * 128 + wn + s * 16 + rsub) * 8);
        }
#pragma unroll
        for (int s = 0; s < 4; ++s)
#pragma unroll
            for (int n = 0; n < 4; ++n)
                acc[s][n] = __builtin_amdgcn_mfma_f32_16x16x32_bf16(
                    __builtin_bit_cast(bf16x8, af[s]), __builtin_bit_cast(bf16x8, bq[n]),
                    acc[s][n], 0, 0, 0);
        __syncthreads();
    }

    // C/D layout: col = lane&15, row = (lane>>4)*4 + reg
    const int rowBase = rowTile + wm + q * 4;
    const int colBase = colTile + wn + rsub;
    if constexpr (MODE == 1) {
        const float beta = *betaPtr;
        short* Sc = (short*)Cout;
        float ncol[4];
#pragma unroll
        for (int n = 0; n < 4; ++n) ncol[n] = sqrtf(nsq[colBase + n * 16]);
#pragma unroll
        for (int s = 0; s < 4; ++s) {
#pragma unroll
            for (int r = 0; r < 4; ++r) {
                const int row = rowBase + s * 16 + r;
                const float nr = sqrtf(nsq[row]);
#pragma unroll
                for (int n = 0; n < 4; ++n) {
                    const int col = colBase + n * 16;
                    float v = acc[s][n][r] * beta / (nr * ncol[n] + EPSV);
                    v += (1.f - adj[(size_t)row * NN + col]) * NEGV;
                    Sc[(size_t)row * NN + col] = f2bf(v);
                }
            }
        }
    } else {
        float* O = (float*)Cout;
#pragma unroll
        for (int s = 0; s < 4; ++s)
#pragma unroll
            for (int r = 0; r < 4; ++r) {
                const int row = rowBase + s * 16 + r;
#pragma unroll
                for (int n = 0; n < 4; ++n)
                    O[(size_t)row * NN + colBase + n * 16] = acc[s][n][r];
            }
    }
}

// In-place row softmax over 4096 bf16 logits; masked entries (-1e9) -> exp = 0.
__global__ __launch_bounds__(256) void softmax_rows(short* __restrict__ S) {
    const int t = threadIdx.x;
    short* rp = S + (size_t)blockIdx.x * NN;
    short8 v0 = ((const short8*)rp)[2 * t];
    short8 v1 = ((const short8*)rp)[2 * t + 1];
    float f[16];
#pragma unroll
    for (int i = 0; i < 8; ++i) {
        f[i] = bf2f(v0[i]);
        f[8 + i] = bf2f(v1[i]);
    }
    float m = f[0];
#pragma unroll
    for (int i = 1; i < 16; ++i) m = fmaxf(m, f[i]);
#pragma unroll
    for (int off = 32; off > 0; off >>= 1) m = fmaxf(m, __shfl_xor(m, off, 64));
    __shared__ float redm[4], reds[4];
    if ((t & 63) == 0) redm[t >> 6] = m;
    __syncthreads();
    m = fmaxf(fmaxf(redm[0], redm[1]), fmaxf(redm[2], redm[3]));
    float sum = 0.f;
#pragma unroll
    for (int i = 0; i < 16; ++i) {
        f[i] = __expf(f[i] - m);
        sum += f[i];
    }
#pragma unroll
    for (int off = 32; off > 0; off >>= 1) sum += __shfl_xor(sum, off, 64);
    if ((t & 63) == 0) reds[t >> 6] = sum;
    __syncthreads();
    sum = reds[0] + reds[1] + reds[2] + reds[3];
    const float rl = 1.f / sum;
    short8 o0, o1;
#pragma unroll
    for (int i = 0; i < 8; ++i) {
        o0[i] = f2bf(f[i] * rl);
        o1[i] = f2bf(f[8 + i] * rl);
    }
    ((short8*)rp)[2 * t] = o0;
    ((short8*)rp)[2 * t + 1] = o1;
}

extern "C" void kernel_launch(void* const* d_in, const int* in_sizes, int n_in,
                              void* d_out, int out_size, void* d_ws, size_t ws_size,
                              hipStream_t stream) {
    const float* x = (const float*)d_in[0];
    const float* adj = (const float*)d_in[1];
    const float* beta = (const float*)d_in[2];

    const size_t MB32 = (size_t)32 * 1024 * 1024;
    if (ws_size < 3 * MB32 + NN * sizeof(float)) return;  // need ~96 MB scratch

    char* ws = (char*)d_ws;
    short* xb = (short*)ws;               // bf16 x          [4096][4096]
    short* xbT = (short*)(ws + MB32);     // bf16 x^T        [4096][4096]
    short* S = (short*)(ws + 2 * MB32);   // bf16 logits / P [4096][4096]
    float* nsq = (float*)(ws + 3 * MB32); // column sumsq    [4096]

    hipMemsetAsync(nsq, 0, NN * sizeof(float), stream);
    col_norm_sq<<<dim3(16, 32), 256, 0, stream>>>(x, nsq);
    cast_transpose<<<dim3(64, 64), dim3(64, 4), 0, stream>>>(x, xb, xbT);
    gemm_nt<1><<<dim3(32, 32), 256, 0, stream>>>(xb, xb, S, nsq, adj, beta);
    softmax_rows<<<NN, 256, 0, stream>>>(S);
    gemm_nt<2><<<dim3(32, 32), 256, 0, stream>>>(S, xbT, d_out, nullptr, nullptr, nullptr);
}